// Round 4
// baseline (368.643 us; speedup 1.0000x reference)
//
#include <hip/hip_runtime.h>
#include <hip/hip_bf16.h>

#define IMG_W 1024
#define IMG_H 1024
#define TH    8           // output rows per block: 2048 blocks -> 8 blocks/CU
#define VX    4           // pixels per thread (float4)
#define NTHREADS 256      // 256*4 = 1024 = full row width

#define ALPHA_ 0.85f
#define BETA_  0.15f
#define C1_    (0.01f * 0.01f)
#define C2_    (0.03f * 0.03f)

struct HRow { float p[VX], t[VX], pp[VX], tt[VX], pt[VX]; };

__device__ __forceinline__ void hzero(HRow& h) {
#pragma unroll
    for (int j = 0; j < VX; ++j) {
        h.p[j] = 0.f; h.t[j] = 0.f; h.pp[j] = 0.f; h.tt[j] = 0.f; h.pt[j] = 0.f;
    }
}

__device__ __forceinline__ void load_row(const float* __restrict__ Pr,
                                         const float* __restrict__ Tr,
                                         int x, float pv[6], float tv[6]) {
    const float4 p4 = *reinterpret_cast<const float4*>(Pr + x);
    const float4 t4 = *reinterpret_cast<const float4*>(Tr + x);
    pv[1] = p4.x; pv[2] = p4.y; pv[3] = p4.z; pv[4] = p4.w;
    tv[1] = t4.x; tv[2] = t4.y; tv[3] = t4.z; tv[4] = t4.w;
    pv[0] = (x > 0)          ? Pr[x - 1]  : 0.f;   // zero-pad at image left edge
    pv[5] = (x + VX < IMG_W) ? Pr[x + VX] : 0.f;   // zero-pad at image right edge
    tv[0] = (x > 0)          ? Tr[x - 1]  : 0.f;
    tv[5] = (x + VX < IMG_W) ? Tr[x + VX] : 0.f;
}

__device__ __forceinline__ void hsum(const float pv[6], const float tv[6], HRow& h) {
#pragma unroll
    for (int j = 0; j < VX; ++j) {
        const float a = pv[j], b = pv[j + 1], c = pv[j + 2];
        const float u = tv[j], v = tv[j + 1], w = tv[j + 2];
        h.p[j]  = a + b + c;
        h.t[j]  = u + v + w;
        h.pp[j] = a * a + b * b + c * c;
        h.tt[j] = u * u + v * v + w * w;
        h.pt[j] = a * u + b * v + c * w;
    }
}

// Each block reduces to one (ssim, l1) pair. MODE=0: write partials to
// ws[2*bid]; MODE=1: atomicAdd into ws[0..1] (small-ws fallback).
// __launch_bounds__(256, 8): 8 waves/EU min -> VGPR capped at 64 so the full
// 32 waves/CU can be resident (R3 lesson: unrolled loop hit 108 VGPR -> 20% occ).
template <int MODE>
__global__ void __launch_bounds__(NTHREADS, 8)
ssim_l1_kernel(const float* __restrict__ pred, const float* __restrict__ tgt,
               float* __restrict__ ws) {
    const int tid = threadIdx.x;
    const int x   = tid * VX;
    const int y0  = blockIdx.y * TH;
    const size_t base = (size_t)blockIdx.z * (size_t)(IMG_W * IMG_H);
    const float* __restrict__ P = pred + base;
    const float* __restrict__ T = tgt + base;

    float ssim_acc = 0.f, l1_acc = 0.f;
    HRow A, B, C;
    float pv[6], tv[6];

    // --- prologue: row y0-1 (may be above the image -> zeros) and row y0 ---
    if (y0 - 1 >= 0) {
        load_row(P + (size_t)(y0 - 1) * IMG_W, T + (size_t)(y0 - 1) * IMG_W, x, pv, tv);
        hsum(pv, tv, A);
    } else {
        hzero(A);
    }
    {
        load_row(P + (size_t)y0 * IMG_W, T + (size_t)y0 * IMG_W, x, pv, tv);
        hsum(pv, tv, B);
#pragma unroll
        for (int k = 1; k <= VX; ++k) l1_acc += fabsf(pv[k] - tv[k]);
    }

    // --- main loop (runtime bounds, NOT unrolled: keeps VGPR ~48) ---
    const float inv9 = 1.0f / 9.0f;
    for (int yo = y0; yo < y0 + TH; ++yo) {
        const int r = yo + 1;   // new bottom row of the vertical window
        if (r < IMG_H) {
            load_row(P + (size_t)r * IMG_W, T + (size_t)r * IMG_W, x, pv, tv);
            hsum(pv, tv, C);
            if (r < y0 + TH) {  // r is a central (owned) row of this block
#pragma unroll
                for (int k = 1; k <= VX; ++k) l1_acc += fabsf(pv[k] - tv[k]);
            }
        } else {
            hzero(C);
        }

#pragma unroll
        for (int j = 0; j < VX; ++j) {
            const float Sp  = A.p[j]  + B.p[j]  + C.p[j];
            const float St  = A.t[j]  + B.t[j]  + C.t[j];
            const float Spp = A.pp[j] + B.pp[j] + C.pp[j];
            const float Stt = A.tt[j] + B.tt[j] + C.tt[j];
            const float Spt = A.pt[j] + B.pt[j] + C.pt[j];

            const float mux  = Sp * inv9;
            const float muy  = St * inv9;
            const float mux2 = mux * mux;
            const float muy2 = muy * muy;
            const float muxy = mux * muy;
            const float sx   = Spp * inv9 - mux2;
            const float sy   = Stt * inv9 - muy2;
            const float sxy  = Spt * inv9 - muxy;

            const float n = (2.0f * muxy + C1_) * (2.0f * sxy + C2_);
            const float d = (mux2 + muy2 + C1_) * (sx + sy + C2_);
            const float ssim = n * __builtin_amdgcn_rcpf(d);  // d >= C1_*C2_ > 0
            float v = 0.5f - 0.5f * ssim;
            v = fminf(fmaxf(v, 0.0f), 1.0f);
            ssim_acc += v;
        }
        A = B;
        B = C;
    }

    // --- reduction: wave shuffle -> LDS across 4 waves -> one write/block ---
    float s = ssim_acc, l = l1_acc;
#pragma unroll
    for (int off = 32; off > 0; off >>= 1) {
        s += __shfl_down(s, off, 64);
        l += __shfl_down(l, off, 64);
    }
    __shared__ float red_s[NTHREADS / 64];
    __shared__ float red_l[NTHREADS / 64];
    const int wid = tid >> 6, lane = tid & 63;
    if (lane == 0) { red_s[wid] = s; red_l[wid] = l; }
    __syncthreads();
    if (tid == 0) {
        float ss = 0.f, ll = 0.f;
#pragma unroll
        for (int w = 0; w < NTHREADS / 64; ++w) { ss += red_s[w]; ll += red_l[w]; }
        if (MODE == 0) {
            const int bid = blockIdx.z * gridDim.y + blockIdx.y;
            ws[2 * bid]     = ss;   // every slot written every call: no pre-zero needed
            ws[2 * bid + 1] = ll;
        } else {
            atomicAdd(&ws[0], ss);
            atomicAdd(&ws[1], ll);
        }
    }
}

__global__ void zero_ws_kernel(float* __restrict__ ws) {
    ws[0] = 0.f;
    ws[1] = 0.f;
}

// Sum nblocks (ssim,l1) pairs from ws and emit the final scalar.
__global__ void __launch_bounds__(256)
finalize_partials_kernel(const float* __restrict__ ws, float* __restrict__ out,
                         int nblocks, float inv_total) {
    const int tid = threadIdx.x;
    float s = 0.f, l = 0.f;
    for (int i = tid; i < nblocks; i += 256) {
        s += ws[2 * i];
        l += ws[2 * i + 1];
    }
#pragma unroll
    for (int off = 32; off > 0; off >>= 1) {
        s += __shfl_down(s, off, 64);
        l += __shfl_down(l, off, 64);
    }
    __shared__ float red_s[4], red_l[4];
    const int wid = tid >> 6, lane = tid & 63;
    if (lane == 0) { red_s[wid] = s; red_l[wid] = l; }
    __syncthreads();
    if (tid == 0) {
        float ss = red_s[0] + red_s[1] + red_s[2] + red_s[3];
        float ll = red_l[0] + red_l[1] + red_l[2] + red_l[3];
        out[0] = ALPHA_ * (ss * inv_total) + BETA_ * (ll * inv_total);
    }
}

__global__ void finalize_atomic_kernel(const float* __restrict__ ws,
                                       float* __restrict__ out, float inv_total) {
    out[0] = ALPHA_ * (ws[0] * inv_total) + BETA_ * (ws[1] * inv_total);
}

extern "C" void kernel_launch(void* const* d_in, const int* in_sizes, int n_in,
                              void* d_out, int out_size, void* d_ws, size_t ws_size,
                              hipStream_t stream) {
    const float* pred = (const float*)d_in[0];
    const float* tgt  = (const float*)d_in[1];
    float* ws = (float*)d_ws;

    const int total = in_sizes[0];                 // N * H * W = 16 * 1024 * 1024
    const int nimg  = total / (IMG_W * IMG_H);     // 16
    const int nblk  = nimg * (IMG_H / TH);         // 16 * 128 = 2048
    const float inv_total = 1.0f / (float)total;

    dim3 grid(1, IMG_H / TH, nimg);

    if (ws_size >= (size_t)(2 * nblk) * sizeof(float)) {
        // partials path: no pre-zero, no atomics
        ssim_l1_kernel<0><<<grid, NTHREADS, 0, stream>>>(pred, tgt, ws);
        finalize_partials_kernel<<<1, 256, 0, stream>>>(ws, (float*)d_out,
                                                        nblk, inv_total);
    } else {
        // fallback: atomic accumulation into ws[0..1]
        zero_ws_kernel<<<1, 1, 0, stream>>>(ws);
        ssim_l1_kernel<1><<<grid, NTHREADS, 0, stream>>>(pred, tgt, ws);
        finalize_atomic_kernel<<<1, 1, 0, stream>>>(ws, (float*)d_out, inv_total);
    }
}

// Round 5
// 150.093 us; speedup vs baseline: 2.4561x; 2.4561x over previous
//
#include <hip/hip_runtime.h>
#include <hip/hip_bf16.h>

#define IMG_W 1024
#define IMG_H 1024
#define TH    8           // output rows per block: 2048 blocks -> 8 blocks/CU
#define VX    4           // pixels per thread (float4)
#define NTHREADS 256      // 256*4 = 1024 = full row width

#define ALPHA_ 0.85f
#define BETA_  0.15f
#define C1_    (0.01f * 0.01f)
#define C2_    (0.03f * 0.03f)

// Per-row horizontal 3-sum stats for VX pixels: 20 floats.
struct RowS { float p[VX], t[VX], pp[VX], tt[VX], pt[VX]; };

__device__ __forceinline__ void rzero(RowS& h) {
#pragma unroll
    for (int j = 0; j < VX; ++j) {
        h.p[j] = 0.f; h.t[j] = 0.f; h.pp[j] = 0.f; h.tt[j] = 0.f; h.pt[j] = 0.f;
    }
}

__device__ __forceinline__ void load_row(const float* __restrict__ Pr,
                                         const float* __restrict__ Tr,
                                         int x, float pv[6], float tv[6]) {
    const float4 p4 = *reinterpret_cast<const float4*>(Pr + x);
    const float4 t4 = *reinterpret_cast<const float4*>(Tr + x);
    pv[1] = p4.x; pv[2] = p4.y; pv[3] = p4.z; pv[4] = p4.w;
    tv[1] = t4.x; tv[2] = t4.y; tv[3] = t4.z; tv[4] = t4.w;
    pv[0] = (x > 0)          ? Pr[x - 1]  : 0.f;   // zero-pad at image left edge
    pv[5] = (x + VX < IMG_W) ? Pr[x + VX] : 0.f;   // zero-pad at image right edge
    tv[0] = (x > 0)          ? Tr[x - 1]  : 0.f;
    tv[5] = (x + VX < IMG_W) ? Tr[x + VX] : 0.f;
}

__device__ __forceinline__ void hsum(const float pv[6], const float tv[6], RowS& h) {
#pragma unroll
    for (int j = 0; j < VX; ++j) {
        const float a = pv[j], b = pv[j + 1], c = pv[j + 2];
        const float u = tv[j], v = tv[j + 1], w = tv[j + 2];
        h.p[j]  = a + b + c;
        h.t[j]  = u + v + w;
        h.pp[j] = a * a + b * b + c * c;
        h.tt[j] = u * u + v * v + w * w;
        h.pt[j] = a * u + b * v + c * w;
    }
}

// Each block reduces to one (ssim, l1) pair. MODE=0: write partials to
// ws[2*bid]; MODE=1: atomicAdd into ws[0..1] (small-ws fallback).
// NOTE (R4 lesson): no min-waves launch bound — forcing 8 waves/EU made the
// allocator spill the row state to scratch (WRITE_SIZE 0.06 -> 557 MB).
// Register pressure is managed structurally instead: 2-row persistent state
// (AB = rowsum(y-1)+rowsum(y), Bp = rowsum(y)) and a rolled row loop
// (R3/R4 lesson: trip-count-8 loops auto-unroll -> 108 VGPR; disable it).
template <int MODE>
__global__ void __launch_bounds__(NTHREADS)
ssim_l1_kernel(const float* __restrict__ pred, const float* __restrict__ tgt,
               float* __restrict__ ws) {
    const int tid = threadIdx.x;
    const int x   = tid * VX;
    const int y0  = blockIdx.y * TH;
    const size_t base = (size_t)blockIdx.z * (size_t)(IMG_W * IMG_H);
    const float* __restrict__ P = pred + base;
    const float* __restrict__ T = tgt + base;

    float ssim_acc = 0.f, l1_acc = 0.f;
    RowS AB, Bp;      // AB = rowsum(yo-1)+rowsum(yo), Bp = rowsum(yo)
    float pv[6], tv[6];

    // --- prologue ---
    if (y0 - 1 >= 0) {
        load_row(P + (size_t)(y0 - 1) * IMG_W, T + (size_t)(y0 - 1) * IMG_W, x, pv, tv);
        hsum(pv, tv, AB);
    } else {
        rzero(AB);
    }
    {
        load_row(P + (size_t)y0 * IMG_W, T + (size_t)y0 * IMG_W, x, pv, tv);
        hsum(pv, tv, Bp);
#pragma unroll
        for (int k = 1; k <= VX; ++k) l1_acc += fabsf(pv[k] - tv[k]);
#pragma unroll
        for (int j = 0; j < VX; ++j) {
            AB.p[j]  += Bp.p[j];  AB.t[j]  += Bp.t[j];
            AB.pp[j] += Bp.pp[j]; AB.tt[j] += Bp.tt[j]; AB.pt[j] += Bp.pt[j];
        }
    }

    const float inv9 = 1.0f / 9.0f;
#pragma clang loop unroll(disable)
    for (int yo = y0; yo < y0 + TH; ++yo) {
        const int r = yo + 1;   // new bottom row of the vertical window
        if (r < IMG_H) {
            load_row(P + (size_t)r * IMG_W, T + (size_t)r * IMG_W, x, pv, tv);
            if (r < y0 + TH) {  // r is an owned row of this block
#pragma unroll
                for (int k = 1; k <= VX; ++k) l1_acc += fabsf(pv[k] - tv[k]);
            }
        } else {
#pragma unroll
            for (int k = 0; k < 6; ++k) { pv[k] = 0.f; tv[k] = 0.f; }
        }

#pragma unroll
        for (int j = 0; j < VX; ++j) {
            // new row's stats, consumed in-flight (no 3rd persistent row)
            const float a = pv[j], b = pv[j + 1], c = pv[j + 2];
            const float u = tv[j], v = tv[j + 1], w = tv[j + 2];
            const float cp  = a + b + c;
            const float ct  = u + v + w;
            const float cpp = a * a + b * b + c * c;
            const float ctt = u * u + v * v + w * w;
            const float cpt = a * u + b * v + c * w;

            const float Sp  = AB.p[j]  + cp;
            const float St  = AB.t[j]  + ct;
            const float Spp = AB.pp[j] + cpp;
            const float Stt = AB.tt[j] + ctt;
            const float Spt = AB.pt[j] + cpt;

            // roll: AB <- Bp + c ; Bp <- c
            AB.p[j]  = Bp.p[j]  + cp;  Bp.p[j]  = cp;
            AB.t[j]  = Bp.t[j]  + ct;  Bp.t[j]  = ct;
            AB.pp[j] = Bp.pp[j] + cpp; Bp.pp[j] = cpp;
            AB.tt[j] = Bp.tt[j] + ctt; Bp.tt[j] = ctt;
            AB.pt[j] = Bp.pt[j] + cpt; Bp.pt[j] = cpt;

            const float mux  = Sp * inv9;
            const float muy  = St * inv9;
            const float mux2 = mux * mux;
            const float muy2 = muy * muy;
            const float muxy = mux * muy;
            const float sx   = Spp * inv9 - mux2;
            const float sy   = Stt * inv9 - muy2;
            const float sxy  = Spt * inv9 - muxy;

            const float n = (2.0f * muxy + C1_) * (2.0f * sxy + C2_);
            const float d = (mux2 + muy2 + C1_) * (sx + sy + C2_);
            const float ssim = n * __builtin_amdgcn_rcpf(d);  // d >= C1_*C2_ > 0
            float vcl = 0.5f - 0.5f * ssim;
            vcl = fminf(fmaxf(vcl, 0.0f), 1.0f);
            ssim_acc += vcl;
        }
    }

    // --- reduction: wave shuffle -> LDS across 4 waves -> one write/block ---
    float s = ssim_acc, l = l1_acc;
#pragma unroll
    for (int off = 32; off > 0; off >>= 1) {
        s += __shfl_down(s, off, 64);
        l += __shfl_down(l, off, 64);
    }
    __shared__ float red_s[NTHREADS / 64];
    __shared__ float red_l[NTHREADS / 64];
    const int wid = tid >> 6, lane = tid & 63;
    if (lane == 0) { red_s[wid] = s; red_l[wid] = l; }
    __syncthreads();
    if (tid == 0) {
        float ss = 0.f, ll = 0.f;
#pragma unroll
        for (int w = 0; w < NTHREADS / 64; ++w) { ss += red_s[w]; ll += red_l[w]; }
        if (MODE == 0) {
            const int bid = blockIdx.z * gridDim.y + blockIdx.y;
            ws[2 * bid]     = ss;   // every slot written every call: no pre-zero needed
            ws[2 * bid + 1] = ll;
        } else {
            atomicAdd(&ws[0], ss);
            atomicAdd(&ws[1], ll);
        }
    }
}

__global__ void zero_ws_kernel(float* __restrict__ ws) {
    ws[0] = 0.f;
    ws[1] = 0.f;
}

// Sum nblocks (ssim,l1) pairs from ws and emit the final scalar.
__global__ void __launch_bounds__(256)
finalize_partials_kernel(const float* __restrict__ ws, float* __restrict__ out,
                         int nblocks, float inv_total) {
    const int tid = threadIdx.x;
    float s = 0.f, l = 0.f;
    for (int i = tid; i < nblocks; i += 256) {
        s += ws[2 * i];
        l += ws[2 * i + 1];
    }
#pragma unroll
    for (int off = 32; off > 0; off >>= 1) {
        s += __shfl_down(s, off, 64);
        l += __shfl_down(l, off, 64);
    }
    __shared__ float red_s[4], red_l[4];
    const int wid = tid >> 6, lane = tid & 63;
    if (lane == 0) { red_s[wid] = s; red_l[wid] = l; }
    __syncthreads();
    if (tid == 0) {
        float ss = red_s[0] + red_s[1] + red_s[2] + red_s[3];
        float ll = red_l[0] + red_l[1] + red_l[2] + red_l[3];
        out[0] = ALPHA_ * (ss * inv_total) + BETA_ * (ll * inv_total);
    }
}

__global__ void finalize_atomic_kernel(const float* __restrict__ ws,
                                       float* __restrict__ out, float inv_total) {
    out[0] = ALPHA_ * (ws[0] * inv_total) + BETA_ * (ws[1] * inv_total);
}

extern "C" void kernel_launch(void* const* d_in, const int* in_sizes, int n_in,
                              void* d_out, int out_size, void* d_ws, size_t ws_size,
                              hipStream_t stream) {
    const float* pred = (const float*)d_in[0];
    const float* tgt  = (const float*)d_in[1];
    float* ws = (float*)d_ws;

    const int total = in_sizes[0];                 // N * H * W = 16 * 1024 * 1024
    const int nimg  = total / (IMG_W * IMG_H);     // 16
    const int nblk  = nimg * (IMG_H / TH);         // 16 * 128 = 2048
    const float inv_total = 1.0f / (float)total;

    dim3 grid(1, IMG_H / TH, nimg);

    if (ws_size >= (size_t)(2 * nblk) * sizeof(float)) {
        // partials path: no pre-zero, no atomics
        ssim_l1_kernel<0><<<grid, NTHREADS, 0, stream>>>(pred, tgt, ws);
        finalize_partials_kernel<<<1, 256, 0, stream>>>(ws, (float*)d_out,
                                                        nblk, inv_total);
    } else {
        // fallback: atomic accumulation into ws[0..1]
        zero_ws_kernel<<<1, 1, 0, stream>>>(ws);
        ssim_l1_kernel<1><<<grid, NTHREADS, 0, stream>>>(pred, tgt, ws);
        finalize_atomic_kernel<<<1, 1, 0, stream>>>(ws, (float*)d_out, inv_total);
    }
}